// Round 7
// baseline (2249.401 us; speedup 1.0000x reference)
//
#include <hip/hip_runtime.h>
#include <hip/hip_bf16.h>

typedef float f32x4 __attribute__((ext_vector_type(4)));
typedef __bf16 bf16x8 __attribute__((ext_vector_type(8)));
typedef unsigned short u16x8 __attribute__((ext_vector_type(8)));
typedef unsigned short u16;

// LDS map (dynamic, 80960 B -> 2 blocks/CU):
//   z    @ 0      65536  [64][512] bf16, XOR-swizzled rows
//   nrm  @ 65536   2048  [64][16] bf16
//   h    @ 67584   9216  [64][72] bf16
//   scl  @ 76800   4096  [64][16] f32
//   gate @ 80896     64  [16] f32
//   enc1 x-stage (8 KB) overlays nrm+h (dead during enc1)
#define SMEM_BYTES 80960
#define Z_OFF 0
#define NRM_OFF 65536
#define H_OFF 67584
#define SCL_OFF 76800
#define GATE_OFF 80896

__device__ __forceinline__ u16 f2bf(float f) {        // native cvt (RNE)
  __bf16 h = (__bf16)f;
  return __builtin_bit_cast(u16, h);
}
__device__ __forceinline__ float bf2f(u16 s) {
  return __uint_as_float(((unsigned int)s) << 16);
}
__device__ __forceinline__ float gelu_f(float x) {
  return 0.5f * x * (1.0f + erff(x * 0.70710678118654752f)); // erf GELU
}
#define MFMA(a, b, c) __builtin_amdgcn_mfma_f32_16x16x32_bf16((a), (b), (c), 0, 0, 0)

// ---------------- merged weight conversion ----------------
__global__ void cvt_all(const float* __restrict__ e1, const float* __restrict__ e2,
                        const float* __restrict__ e3, const float* __restrict__ d1,
                        const float* __restrict__ d2, const float* __restrict__ d3,
                        const float* __restrict__ mx, u16* __restrict__ dst)
{
  int i = blockIdx.x * blockDim.x + threadIdx.x;
  int stride = gridDim.x * blockDim.x;
  for (; i < 3145728; i += stride) {
    float v;
    if (i < 524288)        v = e1[i];
    else if (i < 786432)   v = e2[i - 524288];
    else if (i < 1048576)  v = e3[i - 786432];
    else if (i < 1310720)  v = d1[i - 1048576];
    else if (i < 1572864)  v = d2[i - 1310720];
    else if (i < 2097152)  v = d3[i - 1572864];
    else {
      // mix_w [L,16,16,32,32] (l,bi,j,e,d) -> W[l][o=bi*32+e][k=j*32+d]
      int j = i - 2097152;
      int l = j >> 18, rem = j & 262143;
      int o = rem >> 9, k = rem & 511;
      int bi = o >> 5, e = o & 31, jj = k >> 5, dd = k & 31;
      v = mx[(((l * 16 + bi) * 16 + jj) * 32 + e) * 32 + dd];
    }
    dst[i] = f2bf(v);
  }
}

// ---------------- in-place strip GEMM: z(64x512) x W^T ----------------
// 8 waves; wave wid owns cols [wid*64, wid*64+64): acc[4][4], B-reuse 4.
// K-loop: #pragma unroll 1, b0/b1 dbuf with imm-offset reloads after last use.
// EPI: 0 gelu+bias->z ; 1 bias->z ; 2 latent combine->z ; 3 bias->f32 global
template<int EPI>
__device__ __forceinline__ void gemm512(char* __restrict__ smem,
    const u16* __restrict__ W, const float* __restrict__ bias,
    float* __restrict__ outG, int nOff, int m0)
{
  __syncthreads();                       // previous phase's z writes visible
  const int tid = threadIdx.x;
  const int lane = tid & 63;
  const int wid = tid >> 6;
  const int c0 = wid << 6;
  const int r16 = lane & 15;
  const int kg2 = (lane >> 4) << 4;      // byte k-offset: 0,16,32,48
  const int sw = (r16 & 7) << 4;
  char* z = smem + Z_OFF;
  const char* zrow = z + r16 * 1024;

  const u16* p0 = W + (size_t)(nOff + c0 +  0 + r16) * 512 + (kg2 >> 1);
  const u16* p1 = W + (size_t)(nOff + c0 + 16 + r16) * 512 + (kg2 >> 1);
  const u16* p2 = W + (size_t)(nOff + c0 + 32 + r16) * 512 + (kg2 >> 1);
  const u16* p3 = W + (size_t)(nOff + c0 + 48 + r16) * 512 + (kg2 >> 1);

  f32x4 acc[4][4] = {};
  bf16x8 b0[4], b1[4];
  b0[0] = *(const bf16x8*)p0;        b0[1] = *(const bf16x8*)p1;
  b0[2] = *(const bf16x8*)p2;        b0[3] = *(const bf16x8*)p3;
  b1[0] = *(const bf16x8*)(p0 + 32); b1[1] = *(const bf16x8*)(p1 + 32);
  b1[2] = *(const bf16x8*)(p2 + 32); b1[3] = *(const bf16x8*)(p3 + 32);

  #pragma unroll 1
  for (int ks2 = 0; ks2 < 8; ++ks2) {
    // ---- step A (k-step 2*ks2), operand b0 ----
    {
      const int ka = ((ks2 << 7) | kg2) ^ sw;
      bf16x8 a0 = *(const bf16x8*)(zrow + ka);
      bf16x8 a1 = *(const bf16x8*)(zrow + 16384 + ka);
      __builtin_amdgcn_s_setprio(1);
      #pragma unroll
      for (int nt = 0; nt < 4; ++nt) acc[0][nt] = MFMA(a0, b0[nt], acc[0][nt]);
      bf16x8 a2 = *(const bf16x8*)(zrow + 32768 + ka);
      #pragma unroll
      for (int nt = 0; nt < 4; ++nt) acc[1][nt] = MFMA(a1, b0[nt], acc[1][nt]);
      bf16x8 a3 = *(const bf16x8*)(zrow + 49152 + ka);
      #pragma unroll
      for (int nt = 0; nt < 4; ++nt) acc[2][nt] = MFMA(a2, b0[nt], acc[2][nt]);
      #pragma unroll
      for (int nt = 0; nt < 4; ++nt) acc[3][nt] = MFMA(a3, b0[nt], acc[3][nt]);
      __builtin_amdgcn_s_setprio(0);
      if (ks2 < 7) {                     // reload b0 for next step A (+128 B)
        b0[0] = *(const bf16x8*)(p0 + 64); b0[1] = *(const bf16x8*)(p1 + 64);
        b0[2] = *(const bf16x8*)(p2 + 64); b0[3] = *(const bf16x8*)(p3 + 64);
      }
    }
    // ---- step B (k-step 2*ks2+1), operand b1 ----
    {
      const int kb = ((ks2 << 7) | 64 | kg2) ^ sw;
      bf16x8 a0 = *(const bf16x8*)(zrow + kb);
      bf16x8 a1 = *(const bf16x8*)(zrow + 16384 + kb);
      __builtin_amdgcn_s_setprio(1);
      #pragma unroll
      for (int nt = 0; nt < 4; ++nt) acc[0][nt] = MFMA(a0, b1[nt], acc[0][nt]);
      bf16x8 a2 = *(const bf16x8*)(zrow + 32768 + kb);
      #pragma unroll
      for (int nt = 0; nt < 4; ++nt) acc[1][nt] = MFMA(a1, b1[nt], acc[1][nt]);
      bf16x8 a3 = *(const bf16x8*)(zrow + 49152 + kb);
      #pragma unroll
      for (int nt = 0; nt < 4; ++nt) acc[2][nt] = MFMA(a2, b1[nt], acc[2][nt]);
      #pragma unroll
      for (int nt = 0; nt < 4; ++nt) acc[3][nt] = MFMA(a3, b1[nt], acc[3][nt]);
      __builtin_amdgcn_s_setprio(0);
      if (ks2 < 7) {                     // reload b1 for next step B (+192 B)
        b1[0] = *(const bf16x8*)(p0 + 96); b1[1] = *(const bf16x8*)(p1 + 96);
        b1[2] = *(const bf16x8*)(p2 + 96); b1[3] = *(const bf16x8*)(p3 + 96);
      }
    }
    p0 += 64; p1 += 64; p2 += 64; p3 += 64;
  }

  __syncthreads();                       // all waves done reading z

  const float* scl = (const float*)(smem + SCL_OFF);
  const float* gateL = (const float*)(smem + GATE_OFF);
  #pragma unroll
  for (int nt = 0; nt < 4; ++nt) {
    const int col = c0 + nt * 16 + r16;
    float bv_ = 0.f, gate = 0.f;
    if constexpr (EPI == 0 || EPI == 1 || EPI == 3) bv_ = bias[nOff + col];
    if constexpr (EPI == 2) gate = gateL[col >> 5];
    #pragma unroll
    for (int mt = 0; mt < 4; ++mt) {
      #pragma unroll
      for (int r = 0; r < 4; ++r) {
        const int row = mt * 16 + ((lane >> 4) << 2) + r;
        float v = acc[mt][nt][r];
        if constexpr (EPI == 3) {
          outG[(size_t)(m0 + row) * 1024 + nOff + col] = v + bv_;
        } else {
          char* zp = z + row * 1024 + ((col << 1) ^ ((row & 7) << 4));
          if constexpr (EPI == 0)      *(u16*)zp = f2bf(gelu_f(v + bv_));
          else if constexpr (EPI == 1) *(u16*)zp = f2bf(v + bv_);
          else {
            float sc = scl[row * 16 + (col >> 5)];
            float zo = bf2f(*(const u16*)zp);
            *(u16*)zp = f2bf(zo * (1.f + sc) + gate * v);
          }
        }
      }
    }
  }
}

// ---------------- bundle norms -> MLP -> softplus scales (+gates) ----------------
__device__ __forceinline__ void norm_phase(char* __restrict__ smem,
    const float* __restrict__ w1, const float* __restrict__ b1,
    const float* __restrict__ w2, const float* __restrict__ b2,
    const float* __restrict__ w3, const float* __restrict__ gb)
{
  __syncthreads();
  const int tid = threadIdx.x;
  const int lane = tid & 63;
  const int wv = tid >> 6;
  u16* nrmb = (u16*)(smem + NRM_OFF);      // [64][16] bf16
  u16* h    = (u16*)(smem + H_OFF);        // [64][72] bf16
  float* scl = (float*)(smem + SCL_OFF);
  float* gateL = (float*)(smem + GATE_OFF);
  const char* z = smem + Z_OFF;

  // N1: one wave per row; lane L holds elems [8L,8L+8) -> bundle = L>>2 (derived;
  // r6's ^((row>>2)&1) was a bug)
  #pragma unroll
  for (int p = 0; p < 8; ++p) {
    const int row = p * 8 + wv;
    u16x8 v = *(const u16x8*)(z + row * 1024 + ((lane << 4) ^ ((row & 7) << 4)));
    float ss = 0.f;
    #pragma unroll
    for (int j = 0; j < 8; ++j) { float f = bf2f(v[j]); ss += f * f; }
    ss += __shfl_xor(ss, 1);
    ss += __shfl_xor(ss, 2);
    if ((lane & 3) == 0) nrmb[row * 16 + (lane >> 2)] = f2bf(sqrtf(ss) + 1e-8f);
  }
  if (tid < 16) gateL[tid] = 1.f / (1.f + expf(-gb[tid]));
  __syncthreads();

  // N2: wave wv owns rows wv*8..wv*8+7; lane j computes h1[row][j]
  {
    const float4* w1r = (const float4*)(w1 + lane * 16);
    float4 wv4[4];
    #pragma unroll
    for (int q = 0; q < 4; ++q) wv4[q] = w1r[q];
    float a[8];
    #pragma unroll
    for (int p = 0; p < 8; ++p) a[p] = b1[lane];
    #pragma unroll
    for (int q = 0; q < 4; ++q) {
      #pragma unroll
      for (int t = 0; t < 4; ++t) {
        const int i = q * 4 + t;
        const float w = ((const float*)&wv4[q])[t];
        #pragma unroll
        for (int p = 0; p < 8; ++p)
          a[p] += bf2f(nrmb[(wv * 8 + p) * 16 + i]) * w;
      }
    }
    #pragma unroll
    for (int p = 0; p < 8; ++p) h[(wv * 8 + p) * 72 + lane] = f2bf(gelu_f(a[p]));
  }
  __syncthreads();
  // N3: h = gelu(h @ w2^T + b2); rows wave-local, vectorized h reads
  {
    float a[8];
    #pragma unroll
    for (int p = 0; p < 8; ++p) a[p] = b2[lane];
    const float4* w2r = (const float4*)(w2 + lane * 64);
    #pragma unroll
    for (int k8 = 0; k8 < 8; ++k8) {
      float4 wA = w2r[k8 * 2], wB = w2r[k8 * 2 + 1];
      #pragma unroll
      for (int p = 0; p < 8; ++p) {
        u16x8 hv = *(const u16x8*)(h + (wv * 8 + p) * 72 + k8 * 8);
        a[p] += bf2f(hv[0]) * wA.x + bf2f(hv[1]) * wA.y + bf2f(hv[2]) * wA.z + bf2f(hv[3]) * wA.w
              + bf2f(hv[4]) * wB.x + bf2f(hv[5]) * wB.y + bf2f(hv[6]) * wB.z + bf2f(hv[7]) * wB.w;
      }
    }
    // wave-local rows: reads (program-order) precede writes within the wave
    #pragma unroll
    for (int p = 0; p < 8; ++p) h[(wv * 8 + p) * 72 + lane] = f2bf(gelu_f(a[p]));
  }
  __syncthreads();
  // N4: scl = softplus(h2 @ w3^T): rows r0, r0+32; b = tid&15
  {
    const int b = tid & 15;
    const int r0 = tid >> 4;               // 0..31
    const float4* w3r = (const float4*)(w3 + b * 64);
    float a0 = 0.f, a1 = 0.f;
    #pragma unroll
    for (int k8 = 0; k8 < 8; ++k8) {
      float4 wA = w3r[k8 * 2], wB = w3r[k8 * 2 + 1];
      u16x8 h0 = *(const u16x8*)(h + r0 * 72 + k8 * 8);
      u16x8 h1v = *(const u16x8*)(h + (r0 + 32) * 72 + k8 * 8);
      a0 += bf2f(h0[0]) * wA.x + bf2f(h0[1]) * wA.y + bf2f(h0[2]) * wA.z + bf2f(h0[3]) * wA.w
          + bf2f(h0[4]) * wB.x + bf2f(h0[5]) * wB.y + bf2f(h0[6]) * wB.z + bf2f(h0[7]) * wB.w;
      a1 += bf2f(h1v[0]) * wA.x + bf2f(h1v[1]) * wA.y + bf2f(h1v[2]) * wA.z + bf2f(h1v[3]) * wA.w
          + bf2f(h1v[4]) * wB.x + bf2f(h1v[5]) * wB.y + bf2f(h1v[6]) * wB.z + bf2f(h1v[7]) * wB.w;
    }
    a0 = (a0 > 20.f) ? a0 : log1pf(expf(a0));
    a1 = (a1 > 20.f) ? a1 : log1pf(expf(a1));
    scl[r0 * 16 + b] = a0;
    scl[(r0 + 32) * 16 + b] = a1;
  }
  __syncthreads();
}

// ---------------- fused network: one block per 64-row strip ----------------
__global__ __launch_bounds__(512, 4)
void ugn_mega(const float* __restrict__ x,
              const float* __restrict__ enc_b1, const float* __restrict__ enc_b2,
              const float* __restrict__ enc_b3,
              const float* __restrict__ mlp1_w, const float* __restrict__ mlp1_b,
              const float* __restrict__ mlp2_w, const float* __restrict__ mlp2_b,
              const float* __restrict__ mlp3_w, const float* __restrict__ gate_b,
              const float* __restrict__ dec_b1, const float* __restrict__ dec_b2,
              const float* __restrict__ dec_b3,
              const u16* __restrict__ wE1, const u16* __restrict__ wE2,
              const u16* __restrict__ wE3, const u16* __restrict__ wMix,
              const u16* __restrict__ wD1, const u16* __restrict__ wD2,
              const u16* __restrict__ wD3, float* __restrict__ out)
{
  extern __shared__ char smem[];
  const int m0 = blockIdx.x << 6;          // 64-row strip
  const int tid = threadIdx.x;
  const int lane = tid & 63;
  const int wid = tid >> 6;
  const int c0 = wid << 6;
  const int r16 = lane & 15;
  const int kg2 = (lane >> 4) << 4;
  const int sw = (r16 & 7) << 4;

  // ===== enc1: z = gelu(x @ wE1^T + b1), K=1024 in 16 LDS-staged chunks =====
  {
    char* stage = smem + NRM_OFF;          // 8KB [64][64] bf16 swizzled
    char* z = smem + Z_OFF;
    const float* xs = x + (size_t)m0 * 1024;
    const int xr = tid >> 3;               // 0..63
    const int kp = (tid & 7) << 3;         // 0..56
    const u16* q0 = wE1 + (size_t)(c0 +  0 + r16) * 1024 + (kg2 >> 1);
    const u16* q1 = wE1 + (size_t)(c0 + 16 + r16) * 1024 + (kg2 >> 1);
    const u16* q2 = wE1 + (size_t)(c0 + 32 + r16) * 1024 + (kg2 >> 1);
    const u16* q3 = wE1 + (size_t)(c0 + 48 + r16) * 1024 + (kg2 >> 1);

    float4 v0 = *(const float4*)(xs + (size_t)xr * 1024 + kp);
    float4 v1 = *(const float4*)(xs + (size_t)xr * 1024 + kp + 4);
    f32x4 acc[4][4] = {};
    #pragma unroll 1
    for (int c = 0; c < 16; ++c) {
      u16x8 u;
      u[0] = f2bf(v0.x); u[1] = f2bf(v0.y); u[2] = f2bf(v0.z); u[3] = f2bf(v0.w);
      u[4] = f2bf(v1.x); u[5] = f2bf(v1.y); u[6] = f2bf(v1.z); u[7] = f2bf(v1.w);
      *(u16x8*)(stage + xr * 128 + ((kp << 1) ^ ((xr & 7) << 4))) = u;
      bf16x8 b0[4], b1v[4];
      b0[0] = *(const bf16x8*)q0;        b0[1] = *(const bf16x8*)q1;
      b0[2] = *(const bf16x8*)q2;        b0[3] = *(const bf16x8*)q3;
      b1v[0] = *(const bf16x8*)(q0 + 32); b1v[1] = *(const bf16x8*)(q1 + 32);
      b1v[2] = *(const bf16x8*)(q2 + 32); b1v[3] = *(const bf16x8*)(q3 + 32);
      __syncthreads();
      if (c < 15) {                        // T14: next chunk's x loads early
        const float* src = xs + (size_t)xr * 1024 + (c + 1) * 64 + kp;
        v0 = *(const float4*)src;
        v1 = *(const float4*)(src + 4);
      }
      #pragma unroll
      for (int ks = 0; ks < 2; ++ks) {
        const int kb = ((ks << 6) | kg2) ^ sw;
        bf16x8 a0 = *(const bf16x8*)(stage + r16 * 128 + kb);
        bf16x8 a1 = *(const bf16x8*)(stage + (16 + r16) * 128 + kb);
        bf16x8 a2 = *(const bf16x8*)(stage + (32 + r16) * 128 + kb);
        bf16x8 a3 = *(const bf16x8*)(stage + (48 + r16) * 128 + kb);
        __builtin_amdgcn_s_setprio(1);
        #pragma unroll
        for (int nt = 0; nt < 4; ++nt) {
          const bf16x8 bb = ks ? b1v[nt] : b0[nt];
          acc[0][nt] = MFMA(a0, bb, acc[0][nt]);
          acc[1][nt] = MFMA(a1, bb, acc[1][nt]);
          acc[2][nt] = MFMA(a2, bb, acc[2][nt]);
          acc[3][nt] = MFMA(a3, bb, acc[3][nt]);
        }
        __builtin_amdgcn_s_setprio(0);
      }
      __syncthreads();
      q0 += 64; q1 += 64; q2 += 64; q3 += 64;
    }
    #pragma unroll
    for (int nt = 0; nt < 4; ++nt) {
      const int col = c0 + nt * 16 + r16;
      const float bb = enc_b1[col];
      #pragma unroll
      for (int mt = 0; mt < 4; ++mt) {
        #pragma unroll
        for (int r = 0; r < 4; ++r) {
          const int row = mt * 16 + ((lane >> 4) << 2) + r;
          *(u16*)(z + row * 1024 + ((col << 1) ^ ((row & 7) << 4))) =
              f2bf(gelu_f(acc[mt][nt][r] + bb));
        }
      }
    }
  }

  // ===== enc2 / enc3 (in-place) =====
  gemm512<0>(smem, wE2, enc_b2, nullptr, 0, m0);
  gemm512<1>(smem, wE3, enc_b3, nullptr, 0, m0);

  // ===== 4 latent layers =====
  #pragma unroll 1
  for (int l = 0; l < 4; ++l) {
    norm_phase(smem, mlp1_w + l * 1024, mlp1_b + l * 64,
               mlp2_w + l * 4096, mlp2_b + l * 64,
               mlp3_w + l * 1024, gate_b + l * 16);
    gemm512<2>(smem, wMix + (size_t)l * 262144, nullptr, nullptr, 0, m0);
  }

  // ===== decoder =====
  gemm512<0>(smem, wD1, dec_b1, nullptr, 0, m0);
  gemm512<0>(smem, wD2, dec_b2, nullptr, 0, m0);
  gemm512<3>(smem, wD3, dec_b3, out, 0, m0);
  gemm512<3>(smem, wD3, dec_b3, out, 512, m0);
}

// ---------------- launch ----------------
extern "C" void kernel_launch(void* const* d_in, const int* in_sizes, int n_in,
                              void* d_out, int out_size, void* d_ws, size_t ws_size,
                              hipStream_t stream)
{
  (void)in_sizes; (void)n_in; (void)out_size; (void)ws_size;
  const float* x      = (const float*)d_in[0];
  const float* enc_w1 = (const float*)d_in[1];
  const float* enc_b1 = (const float*)d_in[2];
  const float* enc_w2 = (const float*)d_in[3];
  const float* enc_b2 = (const float*)d_in[4];
  const float* enc_w3 = (const float*)d_in[5];
  const float* enc_b3 = (const float*)d_in[6];
  const float* mlp1_w = (const float*)d_in[7];
  const float* mlp1_b = (const float*)d_in[8];
  const float* mlp2_w = (const float*)d_in[9];
  const float* mlp2_b = (const float*)d_in[10];
  const float* mlp3_w = (const float*)d_in[11];
  const float* mix_w  = (const float*)d_in[12];
  const float* gate_b = (const float*)d_in[13];
  const float* dec_w1 = (const float*)d_in[14];
  const float* dec_b1 = (const float*)d_in[15];
  const float* dec_w2 = (const float*)d_in[16];
  const float* dec_b2 = (const float*)d_in[17];
  const float* dec_w3 = (const float*)d_in[18];
  const float* dec_b3 = (const float*)d_in[19];

  u16* wBase = (u16*)d_ws;
  u16* wE1 = wBase;
  u16* wE2 = wE1 + 524288;
  u16* wE3 = wE2 + 262144;
  u16* wD1 = wE3 + 262144;
  u16* wD2 = wD1 + 262144;
  u16* wD3 = wD2 + 262144;
  u16* wMix = wD3 + 524288;

  cvt_all<<<512, 256, 0, stream>>>(enc_w1, enc_w2, enc_w3, dec_w1, dec_w2, dec_w3,
                                   mix_w, wBase);

  static int smemSet = 0;
  if (!smemSet) {
    hipFuncSetAttribute(reinterpret_cast<const void*>(&ugn_mega),
                        hipFuncAttributeMaxDynamicSharedMemorySize, SMEM_BYTES);
    smemSet = 1;
  }

  ugn_mega<<<1024, 512, SMEM_BYTES, stream>>>(
      x, enc_b1, enc_b2, enc_b3, mlp1_w, mlp1_b, mlp2_w, mlp2_b, mlp3_w, gate_b,
      dec_b1, dec_b2, dec_b3, wE1, wE2, wE3, wMix, wD1, wD2, wD3, (float*)d_out);
}

// Round 8
// 1823.894 us; speedup vs baseline: 1.2333x; 1.2333x over previous
//
#include <hip/hip_runtime.h>
#include <hip/hip_bf16.h>

typedef float f32x4 __attribute__((ext_vector_type(4)));
typedef __bf16 bf16x8 __attribute__((ext_vector_type(8)));
typedef unsigned short u16x8 __attribute__((ext_vector_type(8)));
typedef unsigned short u16;

// LDS map (dynamic, 80960 B -> 2 blocks/CU):
//   z    @ 0      65536  [64][512] bf16, XOR-swizzled rows
//   nrm  @ 65536   2048  [64][16] bf16
//   h    @ 67584   9216  [64][72] bf16
//   scl  @ 76800   4096  [64][16] f32
//   gate @ 80896     64  [16] f32
//   enc1 x-stage (8 KB) overlays nrm+h (dead during enc1)
#define SMEM_BYTES 80960
#define Z_OFF 0
#define NRM_OFF 65536
#define H_OFF 67584
#define SCL_OFF 76800
#define GATE_OFF 80896

__device__ __forceinline__ u16 f2bf(float f) {        // native cvt (RNE)
  __bf16 h = (__bf16)f;
  return __builtin_bit_cast(u16, h);
}
__device__ __forceinline__ float bf2f(u16 s) {
  return __uint_as_float(((unsigned int)s) << 16);
}
__device__ __forceinline__ float gelu_f(float x) {
  return 0.5f * x * (1.0f + erff(x * 0.70710678118654752f)); // erf GELU
}
#define MFMA(a, b, c) __builtin_amdgcn_mfma_f32_16x16x32_bf16((a), (b), (c), 0, 0, 0)

// ---------------- merged weight conversion ----------------
__global__ void cvt_all(const float* __restrict__ e1, const float* __restrict__ e2,
                        const float* __restrict__ e3, const float* __restrict__ d1,
                        const float* __restrict__ d2, const float* __restrict__ d3,
                        const float* __restrict__ mx, u16* __restrict__ dst)
{
  int i = blockIdx.x * blockDim.x + threadIdx.x;
  int stride = gridDim.x * blockDim.x;
  for (; i < 3145728; i += stride) {
    float v;
    if (i < 524288)        v = e1[i];
    else if (i < 786432)   v = e2[i - 524288];
    else if (i < 1048576)  v = e3[i - 786432];
    else if (i < 1310720)  v = d1[i - 1048576];
    else if (i < 1572864)  v = d2[i - 1310720];
    else if (i < 2097152)  v = d3[i - 1572864];
    else {
      // mix_w [L,16,16,32,32] (l,bi,j,e,d) -> W[l][o=bi*32+e][k=j*32+d]
      int j = i - 2097152;
      int l = j >> 18, rem = j & 262143;
      int o = rem >> 9, k = rem & 511;
      int bi = o >> 5, e = o & 31, jj = k >> 5, dd = k & 31;
      v = mx[(((l * 16 + bi) * 16 + jj) * 32 + e) * 32 + dd];
    }
    dst[i] = f2bf(v);
  }
}

// ---------------- in-place strip GEMM: z(64x512) x W^T ----------------
// 8 waves; wave wid owns cols [wid*64, wid*64+64): acc[4][4], B-reuse 4.
// K-loop: #pragma unroll 1, b0/b1 dbuf with imm-offset reloads after last use.
// EPI: 0 gelu+bias->z ; 1 bias->z ; 2 latent combine->z ; 3 bias->f32 global
template<int EPI>
__device__ __forceinline__ void gemm512(char* __restrict__ smem,
    const u16* __restrict__ W, const float* __restrict__ bias,
    float* __restrict__ outG, int nOff, int m0)
{
  __syncthreads();                       // previous phase's z writes visible
  const int tid = threadIdx.x;
  const int lane = tid & 63;
  const int wid = tid >> 6;
  const int c0 = wid << 6;
  const int r16 = lane & 15;
  const int kg2 = (lane >> 4) << 4;      // byte k-offset: 0,16,32,48
  const int sw = (r16 & 7) << 4;
  char* z = smem + Z_OFF;
  const char* zrow = z + r16 * 1024;

  const u16* p0 = W + (size_t)(nOff + c0 +  0 + r16) * 512 + (kg2 >> 1);
  const u16* p1 = W + (size_t)(nOff + c0 + 16 + r16) * 512 + (kg2 >> 1);
  const u16* p2 = W + (size_t)(nOff + c0 + 32 + r16) * 512 + (kg2 >> 1);
  const u16* p3 = W + (size_t)(nOff + c0 + 48 + r16) * 512 + (kg2 >> 1);

  f32x4 acc[4][4] = {};
  bf16x8 b0[4], b1[4];
  b0[0] = *(const bf16x8*)p0;        b0[1] = *(const bf16x8*)p1;
  b0[2] = *(const bf16x8*)p2;        b0[3] = *(const bf16x8*)p3;
  b1[0] = *(const bf16x8*)(p0 + 32); b1[1] = *(const bf16x8*)(p1 + 32);
  b1[2] = *(const bf16x8*)(p2 + 32); b1[3] = *(const bf16x8*)(p3 + 32);

  #pragma unroll 1
  for (int ks2 = 0; ks2 < 8; ++ks2) {
    // ---- step A (k-step 2*ks2), operand b0 ----
    {
      const int ka = ((ks2 << 7) | kg2) ^ sw;
      bf16x8 a0 = *(const bf16x8*)(zrow + ka);
      bf16x8 a1 = *(const bf16x8*)(zrow + 16384 + ka);
      __builtin_amdgcn_s_setprio(1);
      #pragma unroll
      for (int nt = 0; nt < 4; ++nt) acc[0][nt] = MFMA(a0, b0[nt], acc[0][nt]);
      bf16x8 a2 = *(const bf16x8*)(zrow + 32768 + ka);
      #pragma unroll
      for (int nt = 0; nt < 4; ++nt) acc[1][nt] = MFMA(a1, b0[nt], acc[1][nt]);
      bf16x8 a3 = *(const bf16x8*)(zrow + 49152 + ka);
      #pragma unroll
      for (int nt = 0; nt < 4; ++nt) acc[2][nt] = MFMA(a2, b0[nt], acc[2][nt]);
      #pragma unroll
      for (int nt = 0; nt < 4; ++nt) acc[3][nt] = MFMA(a3, b0[nt], acc[3][nt]);
      __builtin_amdgcn_s_setprio(0);
      if (ks2 < 7) {                     // reload b0 for next step A (+128 B)
        b0[0] = *(const bf16x8*)(p0 + 64); b0[1] = *(const bf16x8*)(p1 + 64);
        b0[2] = *(const bf16x8*)(p2 + 64); b0[3] = *(const bf16x8*)(p3 + 64);
      }
    }
    // ---- step B (k-step 2*ks2+1), operand b1 ----
    {
      const int kb = ((ks2 << 7) | 64 | kg2) ^ sw;
      bf16x8 a0 = *(const bf16x8*)(zrow + kb);
      bf16x8 a1 = *(const bf16x8*)(zrow + 16384 + kb);
      __builtin_amdgcn_s_setprio(1);
      #pragma unroll
      for (int nt = 0; nt < 4; ++nt) acc[0][nt] = MFMA(a0, b1[nt], acc[0][nt]);
      bf16x8 a2 = *(const bf16x8*)(zrow + 32768 + kb);
      #pragma unroll
      for (int nt = 0; nt < 4; ++nt) acc[1][nt] = MFMA(a1, b1[nt], acc[1][nt]);
      bf16x8 a3 = *(const bf16x8*)(zrow + 49152 + kb);
      #pragma unroll
      for (int nt = 0; nt < 4; ++nt) acc[2][nt] = MFMA(a2, b1[nt], acc[2][nt]);
      #pragma unroll
      for (int nt = 0; nt < 4; ++nt) acc[3][nt] = MFMA(a3, b1[nt], acc[3][nt]);
      __builtin_amdgcn_s_setprio(0);
      if (ks2 < 7) {                     // reload b1 for next step B (+192 B)
        b1[0] = *(const bf16x8*)(p0 + 96); b1[1] = *(const bf16x8*)(p1 + 96);
        b1[2] = *(const bf16x8*)(p2 + 96); b1[3] = *(const bf16x8*)(p3 + 96);
      }
    }
    p0 += 64; p1 += 64; p2 += 64; p3 += 64;
  }

  __syncthreads();                       // all waves done reading z

  const float* scl = (const float*)(smem + SCL_OFF);
  const float* gateL = (const float*)(smem + GATE_OFF);
  #pragma unroll
  for (int nt = 0; nt < 4; ++nt) {
    const int col = c0 + nt * 16 + r16;
    float bv_ = 0.f, gate = 0.f;
    if constexpr (EPI == 0 || EPI == 1 || EPI == 3) bv_ = bias[nOff + col];
    if constexpr (EPI == 2) gate = gateL[col >> 5];
    #pragma unroll
    for (int mt = 0; mt < 4; ++mt) {
      #pragma unroll
      for (int r = 0; r < 4; ++r) {
        const int row = mt * 16 + ((lane >> 4) << 2) + r;
        float v = acc[mt][nt][r];
        if constexpr (EPI == 3) {
          outG[(size_t)(m0 + row) * 1024 + nOff + col] = v + bv_;
        } else {
          char* zp = z + row * 1024 + ((col << 1) ^ ((row & 7) << 4));
          if constexpr (EPI == 0)      *(u16*)zp = f2bf(gelu_f(v + bv_));
          else if constexpr (EPI == 1) *(u16*)zp = f2bf(v + bv_);
          else {
            float sc = scl[row * 16 + (col >> 5)];
            float zo = bf2f(*(const u16*)zp);
            *(u16*)zp = f2bf(zo * (1.f + sc) + gate * v);
          }
        }
      }
    }
  }
}

// ---------------- bundle norms -> MLP -> softplus scales (+gates) ----------------
__device__ __forceinline__ void norm_phase(char* __restrict__ smem,
    const float* __restrict__ w1, const float* __restrict__ b1,
    const float* __restrict__ w2, const float* __restrict__ b2,
    const float* __restrict__ w3, const float* __restrict__ gb)
{
  __syncthreads();
  const int tid = threadIdx.x;
  const int lane = tid & 63;
  const int wv = tid >> 6;
  u16* nrmb = (u16*)(smem + NRM_OFF);      // [64][16] bf16
  u16* h    = (u16*)(smem + H_OFF);        // [64][72] bf16
  float* scl = (float*)(smem + SCL_OFF);
  float* gateL = (float*)(smem + GATE_OFF);
  const char* z = smem + Z_OFF;

  // N1: one wave per row; lane L holds elems [8L,8L+8) -> bundle = L>>2
  #pragma unroll
  for (int p = 0; p < 8; ++p) {
    const int row = p * 8 + wv;
    u16x8 v = *(const u16x8*)(z + row * 1024 + ((lane << 4) ^ ((row & 7) << 4)));
    float ss = 0.f;
    #pragma unroll
    for (int j = 0; j < 8; ++j) { float f = bf2f(v[j]); ss += f * f; }
    ss += __shfl_xor(ss, 1);
    ss += __shfl_xor(ss, 2);
    if ((lane & 3) == 0) nrmb[row * 16 + (lane >> 2)] = f2bf(sqrtf(ss) + 1e-8f);
  }
  if (tid < 16) gateL[tid] = 1.f / (1.f + expf(-gb[tid]));
  __syncthreads();

  // N2: wave wv owns rows wv*8..wv*8+7; lane j computes h1[row][j]
  {
    const float4* w1r = (const float4*)(w1 + lane * 16);
    float4 wv4[4];
    #pragma unroll
    for (int q = 0; q < 4; ++q) wv4[q] = w1r[q];
    float a[8];
    #pragma unroll
    for (int p = 0; p < 8; ++p) a[p] = b1[lane];
    #pragma unroll
    for (int q = 0; q < 4; ++q) {
      #pragma unroll
      for (int t = 0; t < 4; ++t) {
        const int i = q * 4 + t;
        const float w = ((const float*)&wv4[q])[t];
        #pragma unroll
        for (int p = 0; p < 8; ++p)
          a[p] += bf2f(nrmb[(wv * 8 + p) * 16 + i]) * w;
      }
    }
    #pragma unroll
    for (int p = 0; p < 8; ++p) h[(wv * 8 + p) * 72 + lane] = f2bf(gelu_f(a[p]));
  }
  __syncthreads();
  // N3: h = gelu(h @ w2^T + b2); rows wave-local, vectorized h reads
  {
    float a[8];
    #pragma unroll
    for (int p = 0; p < 8; ++p) a[p] = b2[lane];
    const float4* w2r = (const float4*)(w2 + lane * 64);
    #pragma unroll
    for (int k8 = 0; k8 < 8; ++k8) {
      float4 wA = w2r[k8 * 2], wB = w2r[k8 * 2 + 1];
      #pragma unroll
      for (int p = 0; p < 8; ++p) {
        u16x8 hv = *(const u16x8*)(h + (wv * 8 + p) * 72 + k8 * 8);
        a[p] += bf2f(hv[0]) * wA.x + bf2f(hv[1]) * wA.y + bf2f(hv[2]) * wA.z + bf2f(hv[3]) * wA.w
              + bf2f(hv[4]) * wB.x + bf2f(hv[5]) * wB.y + bf2f(hv[6]) * wB.z + bf2f(hv[7]) * wB.w;
      }
    }
    #pragma unroll
    for (int p = 0; p < 8; ++p) h[(wv * 8 + p) * 72 + lane] = f2bf(gelu_f(a[p]));
  }
  __syncthreads();
  // N4: scl = softplus(h2 @ w3^T): rows r0, r0+32; b = tid&15
  {
    const int b = tid & 15;
    const int r0 = tid >> 4;               // 0..31
    const float4* w3r = (const float4*)(w3 + b * 64);
    float a0 = 0.f, a1 = 0.f;
    #pragma unroll
    for (int k8 = 0; k8 < 8; ++k8) {
      float4 wA = w3r[k8 * 2], wB = w3r[k8 * 2 + 1];
      u16x8 h0 = *(const u16x8*)(h + r0 * 72 + k8 * 8);
      u16x8 h1v = *(const u16x8*)(h + (r0 + 32) * 72 + k8 * 8);
      a0 += bf2f(h0[0]) * wA.x + bf2f(h0[1]) * wA.y + bf2f(h0[2]) * wA.z + bf2f(h0[3]) * wA.w
          + bf2f(h0[4]) * wB.x + bf2f(h0[5]) * wB.y + bf2f(h0[6]) * wB.z + bf2f(h0[7]) * wB.w;
      a1 += bf2f(h1v[0]) * wA.x + bf2f(h1v[1]) * wA.y + bf2f(h1v[2]) * wA.z + bf2f(h1v[3]) * wA.w
          + bf2f(h1v[4]) * wB.x + bf2f(h1v[5]) * wB.y + bf2f(h1v[6]) * wB.z + bf2f(h1v[7]) * wB.w;
    }
    a0 = (a0 > 20.f) ? a0 : log1pf(expf(a0));
    a1 = (a1 > 20.f) ? a1 : log1pf(expf(a1));
    scl[r0 * 16 + b] = a0;
    scl[(r0 + 32) * 16 + b] = a1;
  }
  __syncthreads();
}

// ---------------- fused network: one block per 64-row strip ----------------
// (512, 2): empirically hipcc VGPR cap = 256/w for 512-thread blocks; w=2 -> 128,
// which fits the counted live set (~120). r7's (512,4) capped at 64 -> total spill.
__global__ __launch_bounds__(512, 2)
void ugn_mega(const float* __restrict__ x,
              const float* __restrict__ enc_b1, const float* __restrict__ enc_b2,
              const float* __restrict__ enc_b3,
              const float* __restrict__ mlp1_w, const float* __restrict__ mlp1_b,
              const float* __restrict__ mlp2_w, const float* __restrict__ mlp2_b,
              const float* __restrict__ mlp3_w, const float* __restrict__ gate_b,
              const float* __restrict__ dec_b1, const float* __restrict__ dec_b2,
              const float* __restrict__ dec_b3,
              const u16* __restrict__ wE1, const u16* __restrict__ wE2,
              const u16* __restrict__ wE3, const u16* __restrict__ wMix,
              const u16* __restrict__ wD1, const u16* __restrict__ wD2,
              const u16* __restrict__ wD3, float* __restrict__ out)
{
  extern __shared__ char smem[];
  const int m0 = blockIdx.x << 6;          // 64-row strip
  const int tid = threadIdx.x;
  const int lane = tid & 63;
  const int wid = tid >> 6;
  const int c0 = wid << 6;
  const int r16 = lane & 15;
  const int kg2 = (lane >> 4) << 4;
  const int sw = (r16 & 7) << 4;

  // ===== enc1: z = gelu(x @ wE1^T + b1), K=1024 in 16 LDS-staged chunks =====
  {
    char* stage = smem + NRM_OFF;          // 8KB [64][64] bf16 swizzled
    char* z = smem + Z_OFF;
    const float* xs = x + (size_t)m0 * 1024;
    const int xr = tid >> 3;               // 0..63
    const int kp = (tid & 7) << 3;         // 0..56
    const u16* q0 = wE1 + (size_t)(c0 +  0 + r16) * 1024 + (kg2 >> 1);
    const u16* q1 = wE1 + (size_t)(c0 + 16 + r16) * 1024 + (kg2 >> 1);
    const u16* q2 = wE1 + (size_t)(c0 + 32 + r16) * 1024 + (kg2 >> 1);
    const u16* q3 = wE1 + (size_t)(c0 + 48 + r16) * 1024 + (kg2 >> 1);

    float4 v0 = *(const float4*)(xs + (size_t)xr * 1024 + kp);
    float4 v1 = *(const float4*)(xs + (size_t)xr * 1024 + kp + 4);
    f32x4 acc[4][4] = {};
    #pragma unroll 1
    for (int c = 0; c < 16; ++c) {
      u16x8 u;
      u[0] = f2bf(v0.x); u[1] = f2bf(v0.y); u[2] = f2bf(v0.z); u[3] = f2bf(v0.w);
      u[4] = f2bf(v1.x); u[5] = f2bf(v1.y); u[6] = f2bf(v1.z); u[7] = f2bf(v1.w);
      *(u16x8*)(stage + xr * 128 + ((kp << 1) ^ ((xr & 7) << 4))) = u;
      bf16x8 b0[4], b1v[4];
      b0[0] = *(const bf16x8*)q0;        b0[1] = *(const bf16x8*)q1;
      b0[2] = *(const bf16x8*)q2;        b0[3] = *(const bf16x8*)q3;
      b1v[0] = *(const bf16x8*)(q0 + 32); b1v[1] = *(const bf16x8*)(q1 + 32);
      b1v[2] = *(const bf16x8*)(q2 + 32); b1v[3] = *(const bf16x8*)(q3 + 32);
      __syncthreads();
      if (c < 15) {                        // T14: next chunk's x loads early
        const float* src = xs + (size_t)xr * 1024 + (c + 1) * 64 + kp;
        v0 = *(const float4*)src;
        v1 = *(const float4*)(src + 4);
      }
      #pragma unroll
      for (int ks = 0; ks < 2; ++ks) {
        const int kb = ((ks << 6) | kg2) ^ sw;
        bf16x8 a0 = *(const bf16x8*)(stage + r16 * 128 + kb);
        bf16x8 a1 = *(const bf16x8*)(stage + (16 + r16) * 128 + kb);
        bf16x8 a2 = *(const bf16x8*)(stage + (32 + r16) * 128 + kb);
        bf16x8 a3 = *(const bf16x8*)(stage + (48 + r16) * 128 + kb);
        __builtin_amdgcn_s_setprio(1);
        #pragma unroll
        for (int nt = 0; nt < 4; ++nt) {
          const bf16x8 bb = ks ? b1v[nt] : b0[nt];
          acc[0][nt] = MFMA(a0, bb, acc[0][nt]);
          acc[1][nt] = MFMA(a1, bb, acc[1][nt]);
          acc[2][nt] = MFMA(a2, bb, acc[2][nt]);
          acc[3][nt] = MFMA(a3, bb, acc[3][nt]);
        }
        __builtin_amdgcn_s_setprio(0);
      }
      __syncthreads();
      q0 += 64; q1 += 64; q2 += 64; q3 += 64;
    }
    #pragma unroll
    for (int nt = 0; nt < 4; ++nt) {
      const int col = c0 + nt * 16 + r16;
      const float bb = enc_b1[col];
      #pragma unroll
      for (int mt = 0; mt < 4; ++mt) {
        #pragma unroll
        for (int r = 0; r < 4; ++r) {
          const int row = mt * 16 + ((lane >> 4) << 2) + r;
          *(u16*)(z + row * 1024 + ((col << 1) ^ ((row & 7) << 4))) =
              f2bf(gelu_f(acc[mt][nt][r] + bb));
        }
      }
    }
  }

  // ===== enc2 / enc3 (in-place) =====
  gemm512<0>(smem, wE2, enc_b2, nullptr, 0, m0);
  gemm512<1>(smem, wE3, enc_b3, nullptr, 0, m0);

  // ===== 4 latent layers =====
  #pragma unroll 1
  for (int l = 0; l < 4; ++l) {
    norm_phase(smem, mlp1_w + l * 1024, mlp1_b + l * 64,
               mlp2_w + l * 4096, mlp2_b + l * 64,
               mlp3_w + l * 1024, gate_b + l * 16);
    gemm512<2>(smem, wMix + (size_t)l * 262144, nullptr, nullptr, 0, m0);
  }

  // ===== decoder =====
  gemm512<0>(smem, wD1, dec_b1, nullptr, 0, m0);
  gemm512<0>(smem, wD2, dec_b2, nullptr, 0, m0);
  gemm512<3>(smem, wD3, dec_b3, out, 0, m0);
  gemm512<3>(smem, wD3, dec_b3, out, 512, m0);
}

// ---------------- launch ----------------
extern "C" void kernel_launch(void* const* d_in, const int* in_sizes, int n_in,
                              void* d_out, int out_size, void* d_ws, size_t ws_size,
                              hipStream_t stream)
{
  (void)in_sizes; (void)n_in; (void)out_size; (void)ws_size;
  const float* x      = (const float*)d_in[0];
  const float* enc_w1 = (const float*)d_in[1];
  const float* enc_b1 = (const float*)d_in[2];
  const float* enc_w2 = (const float*)d_in[3];
  const float* enc_b2 = (const float*)d_in[4];
  const float* enc_w3 = (const float*)d_in[5];
  const float* enc_b3 = (const float*)d_in[6];
  const float* mlp1_w = (const float*)d_in[7];
  const float* mlp1_b = (const float*)d_in[8];
  const float* mlp2_w = (const float*)d_in[9];
  const float* mlp2_b = (const float*)d_in[10];
  const float* mlp3_w = (const float*)d_in[11];
  const float* mix_w  = (const float*)d_in[12];
  const float* gate_b = (const float*)d_in[13];
  const float* dec_w1 = (const float*)d_in[14];
  const float* dec_b1 = (const float*)d_in[15];
  const float* dec_w2 = (const float*)d_in[16];
  const float* dec_b2 = (const float*)d_in[17];
  const float* dec_w3 = (const float*)d_in[18];
  const float* dec_b3 = (const float*)d_in[19];

  u16* wBase = (u16*)d_ws;
  u16* wE1 = wBase;
  u16* wE2 = wE1 + 524288;
  u16* wE3 = wE2 + 262144;
  u16* wD1 = wE3 + 262144;
  u16* wD2 = wD1 + 262144;
  u16* wD3 = wD2 + 262144;
  u16* wMix = wD3 + 524288;

  cvt_all<<<512, 256, 0, stream>>>(enc_w1, enc_w2, enc_w3, dec_w1, dec_w2, dec_w3,
                                   mix_w, wBase);

  static int smemSet = 0;
  if (!smemSet) {
    hipFuncSetAttribute(reinterpret_cast<const void*>(&ugn_mega),
                        hipFuncAttributeMaxDynamicSharedMemorySize, SMEM_BYTES);
    smemSet = 1;
  }

  ugn_mega<<<1024, 512, SMEM_BYTES, stream>>>(
      x, enc_b1, enc_b2, enc_b3, mlp1_w, mlp1_b, mlp2_w, mlp2_b, mlp3_w, gate_b,
      dec_b1, dec_b2, dec_b3, wE1, wE2, wE3, wMix, wD1, wD2, wD3, (float*)d_out);
}